// Round 1
// baseline (74.248 us; speedup 1.0000x reference)
//
#include <hip/hip_runtime.h>

#define N_TYPES 4
#define N_DESC  8
#define K_MAX   8
#define L_MAX   4
#define M_NBR   20
#define NPAIR   (M_NBR * (M_NBR - 1) / 2)   // 190
#define ATOMS_PER_BLOCK 4

constexpr float R_C = 5.0f;
constexpr float PI_F = 3.14159265358979323846f;

__global__ __launch_bounds__(256) void AngularDescriptor_kernel(
    const int*   __restrict__ types,
    const float* __restrict__ pos,
    const int*   __restrict__ nbr,
    const float* __restrict__ c_table,
    float*       __restrict__ out,
    int N)
{
    // per-wave LDS slices (wave = one atom)
    __shared__ float4 sd4[ATOMS_PER_BLOCK][M_NBR];            // (dx,dy,dz,r)
    __shared__ float  sf [ATOMS_PER_BLOCK][M_NBR][K_MAX];     // chebyshev basis
    __shared__ float  sg [ATOMS_PER_BLOCK][M_NBR][N_DESC];    // g_ij[d]
    __shared__ int    stj[ATOMS_PER_BLOCK][M_NBR];            // neighbor types
    __shared__ unsigned short spair[NPAIR];                   // packed (m1<<5)|m2

    const int t    = threadIdx.x;
    const int w    = t >> 6;          // wave index in block
    const int lane = t & 63;
    const int atom = blockIdx.x * ATOMS_PER_BLOCK + w;

    // ---- phase 0: pair LUT (block-wide, identical for every atom) ----
    if (t < NPAIR) {
        int rem = t, m1 = 0;
        while (rem >= M_NBR - 1 - m1) { rem -= M_NBR - 1 - m1; ++m1; }
        spair[t] = (unsigned short)((m1 << 5) | (m1 + 1 + rem));
    }

    float px = 0.f, py = 0.f, pz = 0.f;
    int ti = 0;
    if (atom < N) {
        ti = types[atom];
        px = pos[atom * 3 + 0];
        py = pos[atom * 3 + 1];
        pz = pos[atom * 3 + 2];
    }

    // ---- phase 1a: per-neighbor displacement, r, chebyshev (lanes 0..19) ----
    if (atom < N && lane < M_NBR) {
        const int j = nbr[atom * M_NBR + lane];
        const float dx = pos[j * 3 + 0] - px;
        const float dy = pos[j * 3 + 1] - py;
        const float dz = pos[j * 3 + 2] - pz;
        const float r  = sqrtf(dx * dx + dy * dy + dz * dz);
        sd4[w][lane] = make_float4(dx, dy, dz, r);
        stj[w][lane] = types[j];

        const float fc  = (r < R_C) ? (0.5f * cosf(PI_F * r / R_C) + 0.5f) : 0.0f;
        const float hfc = 0.5f * fc;
        const float u   = r / R_C - 1.0f;
        const float x   = 2.0f * u * u - 1.0f;
        float tkm2 = 1.0f, tkm1 = x;
        sf[w][lane][0] = 2.0f * hfc;            // (T0 + 1) * hfc
        sf[w][lane][1] = (x + 1.0f) * hfc;
        #pragma unroll
        for (int k = 2; k < K_MAX; ++k) {
            const float tk = 2.0f * x * tkm1 - tkm2;
            sf[w][lane][k] = (tk + 1.0f) * hfc;
            tkm2 = tkm1; tkm1 = tk;
        }
    }
    __syncthreads();

    const int d = lane & 7;   // descriptor owned by this lane
    const int g = lane >> 3;  // pair-group

    // ---- phase 1b: g[m][d] = sum_k c[ti][tj][d][k] * f[m][k] ----
    if (atom < N) {
        for (int m = g; m < M_NBR; m += 8) {
            const int tj = stj[w][m];
            const float* c = c_table + (((ti * N_TYPES + tj) * N_DESC + d) * K_MAX);
            const float4 c0 = ((const float4*)c)[0];
            const float4 c1 = ((const float4*)c)[1];
            const float* f = sf[w][m];
            const float acc = c0.x * f[0] + c0.y * f[1] + c0.z * f[2] + c0.w * f[3]
                            + c1.x * f[4] + c1.y * f[5] + c1.z * f[6] + c1.w * f[7];
            sg[w][m][d] = acc;
        }
    }
    __syncthreads();

    // ---- phase 2: pair loop; lane accumulates its d over all 4 Legendre l ----
    float a0 = 0.f, a1 = 0.f, a2 = 0.f, a3 = 0.f;
    if (atom < N) {
        for (int p = g; p < NPAIR; p += 8) {
            const int pe = spair[p];
            const int m1 = pe >> 5, m2 = pe & 31;
            const float4 v1 = sd4[w][m1];
            const float4 v2 = sd4[w][m2];
            const float dot   = v1.x * v2.x + v1.y * v2.y + v1.z * v2.z;
            const float denom = v1.w * v2.w + 1e-8f;
            const float c  = dot * __builtin_amdgcn_rcpf(denom);
            const float gg = sg[w][m1][d] * sg[w][m2][d];
            const float P2 = 1.5f * c * c - 0.5f;
            const float P3 = (5.0f * c * P2 - 2.0f * c) * (1.0f / 3.0f);
            a0 += gg;
            a1 = fmaf(gg, c,  a1);
            a2 = fmaf(gg, P2, a2);
            a3 = fmaf(gg, P3, a3);
        }
    }

    // ---- phase 3: reduce across the 8 pair-groups (lanes strided by 8) ----
    #pragma unroll
    for (int off = 8; off <= 32; off <<= 1) {
        a0 += __shfl_xor(a0, off, 64);
        a1 += __shfl_xor(a1, off, 64);
        a2 += __shfl_xor(a2, off, 64);
        a3 += __shfl_xor(a3, off, 64);
    }

    // ---- phase 4: lanes 0..7 write q[i][d][0..3] as one float4 ----
    if (atom < N && lane < 8) {
        ((float4*)out)[atom * N_DESC + d] = make_float4(a0, a1, a2, a3);
    }
}

extern "C" void kernel_launch(void* const* d_in, const int* in_sizes, int n_in,
                              void* d_out, int out_size, void* d_ws, size_t ws_size,
                              hipStream_t stream) {
    const int*   types   = (const int*)  d_in[0];
    const float* pos     = (const float*)d_in[1];
    const int*   nbr     = (const int*)  d_in[2];
    const float* c_table = (const float*)d_in[3];
    float*       out     = (float*)      d_out;

    const int N = in_sizes[0];
    const int grid = (N + ATOMS_PER_BLOCK - 1) / ATOMS_PER_BLOCK;
    AngularDescriptor_kernel<<<grid, 256, 0, stream>>>(types, pos, nbr, c_table, out, N);
}

// Round 2
// 66.083 us; speedup vs baseline: 1.1235x; 1.1235x over previous
//
#include <hip/hip_runtime.h>

#define N_TYPES 4
#define N_DESC  8
#define K_MAX   8
#define L_MAX   4
#define M_NBR   20
#define NCOMP   20                   // 1 (l0) + 3 (l1) + 6 (l2) + 10 (l3)
#define ATOMS_PER_BLOCK 4

constexpr float R_C  = 5.0f;
constexpr float SQ2  = 1.41421356237309515f;
constexpr float SQ3  = 1.73205080756887729f;
constexpr float SQ6  = 2.44948974968163702f;

// q[i][d][l] = sum_{j<k} g_ijd * g_ikd * P_l(cos theta_jk)
// Addition theorem: P_l(u.v) = scale_l * F_l(u).F_l(v) for unit u,v, with
// F built from traceless symmetric tensor components (20 comps for l=0..3,
// scale = {1, 1, 3/2, 5/2}).  So
//   q[d][l] = 0.5*scale_l*|A_l|^2 - 0.5*G2,  A_l = sum_j g_jd F_l(u_j),
//   G2 = sum_j g_jd^2.   O(M) instead of O(M^2) pairs.
__global__ __launch_bounds__(256) void AngularDescriptor_kernel(
    const int*   __restrict__ types,
    const float* __restrict__ pos,
    const int*   __restrict__ nbr,
    const float* __restrict__ c_table,
    float*       __restrict__ out,
    int N)
{
    __shared__ float sfeat[ATOMS_PER_BLOCK][NCOMP][M_NBR];  // F^T: [comp][nbr]
    __shared__ float scheb[ATOMS_PER_BLOCK][M_NBR][K_MAX];  // chebyshev basis
    __shared__ float sg   [ATOMS_PER_BLOCK][N_DESC][M_NBR]; // g^T: [d][nbr]
    __shared__ int   stj  [ATOMS_PER_BLOCK][M_NBR];         // neighbor types

    const int t    = threadIdx.x;
    const int w    = t >> 6;
    const int lane = t & 63;
    const int atom = blockIdx.x * ATOMS_PER_BLOCK + w;

    float px = 0.f, py = 0.f, pz = 0.f;
    int ti = 0;
    if (atom < N) {
        ti = types[atom];
        px = pos[atom * 3 + 0];
        py = pos[atom * 3 + 1];
        pz = pos[atom * 3 + 2];
    }

    // ---- phase 1a: one lane per neighbor: r, chebyshev, unit vec, features ----
    if (atom < N && lane < M_NBR) {
        const int j = nbr[atom * M_NBR + lane];
        const float dx = pos[j * 3 + 0] - px;
        const float dy = pos[j * 3 + 1] - py;
        const float dz = pos[j * 3 + 2] - pz;
        const float r2   = dx * dx + dy * dy + dz * dz;
        const float rinv = __builtin_amdgcn_rsqf(r2);
        const float r    = r2 * rinv;

        // chebyshev * 0.5*fc   (v_cos_f32 takes revolutions: pi*r/rc -> r/(2rc))
        const float fc  = (r < R_C) ? (0.5f * __builtin_amdgcn_cosf(r * (0.5f / R_C)) + 0.5f)
                                    : 0.0f;
        const float hfc = 0.5f * fc;
        const float u   = r * (1.0f / R_C) - 1.0f;
        const float x   = 2.0f * u * u - 1.0f;
        float ch[K_MAX];
        ch[0] = 2.0f * hfc;
        ch[1] = (x + 1.0f) * hfc;
        float tkm2 = 1.0f, tkm1 = x;
        #pragma unroll
        for (int k = 2; k < K_MAX; ++k) {
            const float tk = 2.0f * x * tkm1 - tkm2;
            ch[k] = (tk + 1.0f) * hfc;
            tkm2 = tkm1; tkm1 = tk;
        }
        ((float4*)&scheb[w][lane][0])[0] = make_float4(ch[0], ch[1], ch[2], ch[3]);
        ((float4*)&scheb[w][lane][0])[1] = make_float4(ch[4], ch[5], ch[6], ch[7]);
        stj[w][lane] = types[j];

        // unit vector + tensor features
        const float ux = dx * rinv, uy = dy * rinv, uz = dz * rinv;
        const float x2 = ux * ux, y2 = uy * uy, z2 = uz * uz;
        float F[NCOMP];
        F[0]  = 1.0f;                       // l=0
        F[1]  = ux;  F[2] = uy;  F[3] = uz; // l=1
        F[4]  = x2 - (1.0f / 3.0f);         // l=2 (scale 3/2)
        F[5]  = y2 - (1.0f / 3.0f);
        F[6]  = z2 - (1.0f / 3.0f);
        F[7]  = SQ2 * ux * uy;
        F[8]  = SQ2 * ux * uz;
        F[9]  = SQ2 * uy * uz;
        F[10] = ux * (x2 - 0.6f);           // l=3 (scale 5/2)
        F[11] = uy * (y2 - 0.6f);
        F[12] = uz * (z2 - 0.6f);
        F[13] = SQ3 * uy * (x2 - 0.2f);     // xxy
        F[14] = SQ3 * uz * (x2 - 0.2f);     // xxz
        F[15] = SQ3 * ux * (y2 - 0.2f);     // xyy
        F[16] = SQ3 * uz * (y2 - 0.2f);     // yyz
        F[17] = SQ3 * ux * (z2 - 0.2f);     // xzz
        F[18] = SQ3 * uy * (z2 - 0.2f);     // yzz
        F[19] = SQ6 * ux * uy * uz;
        #pragma unroll
        for (int c = 0; c < NCOMP; ++c) sfeat[w][c][lane] = F[c];
    }
    __syncthreads();

    const int d  = lane & 7;
    const int gp = lane >> 3;

    // ---- phase 1b: g^T[d][m] = sum_k c_table[ti][tj][d][k] * cheb[m][k] ----
    if (atom < N) {
        #pragma unroll
        for (int m = gp; m < M_NBR; m += 8) {
            const int tj = stj[w][m];
            const float* c = c_table + (((ti * N_TYPES + tj) * N_DESC + d) * K_MAX);
            const float4 c0 = ((const float4*)c)[0];
            const float4 c1 = ((const float4*)c)[1];
            const float4 f0 = ((const float4*)&scheb[w][m][0])[0];
            const float4 f1 = ((const float4*)&scheb[w][m][0])[1];
            sg[w][d][m] = c0.x * f0.x + c0.y * f0.y + c0.z * f0.z + c0.w * f0.w
                        + c1.x * f1.x + c1.y * f1.y + c1.z * f1.z + c1.w * f1.w;
        }
    }
    __syncthreads();

    // ---- phase 2: lane (d, cg) accumulates A_c = sum_m g[m]*F[c][m] ----
    float p0 = 0.f, p1 = 0.f, p2 = 0.f, p3 = 0.f;
    float hG2 = 0.f;
    if (atom < N) {
        float g[M_NBR];
        #pragma unroll
        for (int i = 0; i < 5; ++i) {
            const float4 v = ((const float4*)&sg[w][d][0])[i];
            g[4*i+0] = v.x; g[4*i+1] = v.y; g[4*i+2] = v.z; g[4*i+3] = v.w;
        }
        float G2 = 0.f;
        #pragma unroll
        for (int m = 0; m < M_NBR; ++m) G2 = fmaf(g[m], g[m], G2);
        hG2 = 0.5f * G2;

        #pragma unroll
        for (int s = 0; s < 3; ++s) {
            const int c = gp + 8 * s;
            if (c < NCOMP) {
                float acc = 0.f;
                #pragma unroll
                for (int i = 0; i < 5; ++i) {
                    const float4 v = ((const float4*)&sfeat[w][c][0])[i];
                    acc = fmaf(g[4*i+0], v.x, acc);
                    acc = fmaf(g[4*i+1], v.y, acc);
                    acc = fmaf(g[4*i+2], v.z, acc);
                    acc = fmaf(g[4*i+3], v.w, acc);
                }
                const float v2 = acc * acc;
                if      (c == 0)  p0 += 0.50f * v2;
                else if (c <= 3)  p1 += 0.50f * v2;
                else if (c <= 9)  p2 += 0.75f * v2;
                else              p3 += 1.25f * v2;
            }
        }
    }

    // ---- phase 3: reduce partial l-sums across the 8 comp-groups ----
    #pragma unroll
    for (int off = 8; off <= 32; off <<= 1) {
        p0 += __shfl_xor(p0, off, 64);
        p1 += __shfl_xor(p1, off, 64);
        p2 += __shfl_xor(p2, off, 64);
        p3 += __shfl_xor(p3, off, 64);
    }

    // ---- phase 4: lanes 0..7 write q[i][d][0..3] ----
    if (atom < N && lane < 8) {
        ((float4*)out)[atom * N_DESC + d] =
            make_float4(p0 - hG2, p1 - hG2, p2 - hG2, p3 - hG2);
    }
}

extern "C" void kernel_launch(void* const* d_in, const int* in_sizes, int n_in,
                              void* d_out, int out_size, void* d_ws, size_t ws_size,
                              hipStream_t stream) {
    const int*   types   = (const int*)  d_in[0];
    const float* pos     = (const float*)d_in[1];
    const int*   nbr     = (const int*)  d_in[2];
    const float* c_table = (const float*)d_in[3];
    float*       out     = (float*)      d_out;

    const int N = in_sizes[0];
    const int grid = (N + ATOMS_PER_BLOCK - 1) / ATOMS_PER_BLOCK;
    AngularDescriptor_kernel<<<grid, 256, 0, stream>>>(types, pos, nbr, c_table, out, N);
}